// Round 11
// baseline (99.671 us; speedup 1.0000x reference)
//
#include <hip/hip_runtime.h>
#include <math.h>

// ---------------------------------------------------------------------------
// NFFT forward (type-2): f_hat (B,C,256,256 complex) -> samples at M points.
// 3 dispatches. Workspace layout (256 MB available; we use 6 MB):
//   Grows (bf16x4): [b][256][512] uint2  @ 0      (2 x 1 MB, compact nonzero rows)
//   Gcols (bf16x4): [b][512][512] uint2  @ 2 MB   (2 x 2 MB, full col-FFT'd grid)
// rows: channel-merged deconvolve/pad/fftshift + row FFT (fp32 in LDS),
//       output packed bf16x4 (rounding layer 1).
// cols: reads bf16 rows, fp32 FFT in LDS, packs bf16x4 (rounding layer 2).
// gather: 8 lanes per point, TWO points per lane-group (16 tap-loads in
//       flight per wave — R10 analysis: gather is latency x MLP bound at
//       ~0.9 lines/cy; doubling MLP pushes toward the 1/cy TA ceiling).
// Shift algebra: ifftshift(FFT(fftshift(p)))[(ind+256)%512] == FFT(fftshift(p))[ind&511].
// Output PLANAR: real plane (B,C,M) then imag plane.
// R4: no forced __launch_bounds__ minima. R5: coalesce scattered gathers.
// R8: never cooperative grid.sync. R10: ~45us of dur is harness ws-poison
// (untouchable floor); our controllable budget is ~54us.
// ---------------------------------------------------------------------------

#define NGRID 512
#define NSMALL 256
#define MW 4
#define BB 2
#define CC 2
#define MPTS 200000
#define PLANE (BB * CC * MPTS)   // imag-plane offset in floats
#define LPAD4 513                // LDS pitch in float4 (breaks pow2 banking)
#define GROWS_B 131072           // uint2 per b-image in Grows (256*512)
#define GCOLS_OFF 262144         // uint2 offset of Gcols region (2 MB)
#define GCOLS_B 262144           // uint2 per b-image in Gcols (512*512)

// I0(z) asymptotic series, valid z > 8 (our z in [17.7, 18.9])
__device__ __forceinline__ float nfft29781_i0_large(float z) {
    float inv = 1.0f / z;
    float p = 1.0f + inv * (0.125f + inv * (0.0703125f
              + inv * (0.0732421875f + inv * 0.112152099609375f)));
    return expf(z) * rsqrtf(2.0f * (float)M_PI * z) * p;
}

__device__ __forceinline__ int nfft29781_brev9(int v) {
    return (int)(__brev((unsigned)v) >> 23);
}

__device__ __forceinline__ unsigned nfft29781_bf16pack(float a, float b) {
    unsigned ua = __float_as_uint(a);
    ua += 0x7FFFu + ((ua >> 16) & 1u);           // RNE
    unsigned ub = __float_as_uint(b);
    ub += 0x7FFFu + ((ub >> 16) & 1u);
    return (ua >> 16) | (ub & 0xFFFF0000u);
}

__device__ __forceinline__ float4 nfft29781_unpk(uint2 g) {
    return make_float4(__uint_as_float(g.x << 16),
                       __uint_as_float(g.x & 0xFFFF0000u),
                       __uint_as_float(g.y << 16),
                       __uint_as_float(g.y & 0xFFFF0000u));
}

// 512-pt radix-2 DIT FFT on complex PAIRS (float4 = two complexes), in LDS.
__device__ __forceinline__ void nfft29781_fft512_c2(float4* s, int tid) {
    #pragma unroll
    for (int st = 0; st < 9; ++st) {
        int half = 1 << st;
        int pos = tid & (half - 1);
        int i0 = ((tid >> st) << (st + 1)) + pos;
        int i1 = i0 + half;
        float ang = -(float)M_PI * (float)pos / (float)half;
        float sn, cs;
        __sincosf(ang, &sn, &cs);
        float4 a = s[i0];
        float4 b = s[i1];
        float4 tw;
        tw.x = b.x * cs - b.y * sn;  tw.y = b.x * sn + b.y * cs;
        tw.z = b.z * cs - b.w * sn;  tw.w = b.z * sn + b.w * cs;
        s[i0] = make_float4(a.x + tw.x, a.y + tw.y, a.z + tw.z, a.w + tw.w);
        s[i1] = make_float4(a.x - tw.x, a.y - tw.y, a.z - tw.z, a.w - tw.w);
        __syncthreads();
    }
}

// ---------------------------------------------------------------------------
// Rows: one block per (b, a1); both channels in a float4. Output packed bf16
// into compact Grows[b][q][col], q = a1 ^ 128 (verified: a1=0->j1=384->q=128).
// ---------------------------------------------------------------------------
__global__ __launch_bounds__(256) void nfft29781_rows3(const float* __restrict__ fr,
                                                       const float* __restrict__ fi,
                                                       uint2* __restrict__ Grows) {
    __shared__ float4 s[NGRID];
    int tid = threadIdx.x;
    int b   = blockIdx.x >> 8;
    int a1  = blockIdx.x & 255;

    const float bcon  = 1.5f * (float)M_PI;
    const float scale = 2.0f * (float)M_PI / (float)NGRID;
    float k1 = (float)(a1 - 128) * scale;
    float p1 = nfft29781_i0_large((float)MW * sqrtf(bcon * bcon - k1 * k1));

    int a2 = tid ^ 128;
    float k2 = (float)(a2 - 128) * scale;
    float p2 = nfft29781_i0_large((float)MW * sqrtf(bcon * bcon - k2 * k2));
    float invp = 1.0f / (p1 * p2);

    size_t s0 = ((size_t)(b * CC + 0) * NSMALL + a1) * NSMALL + a2;
    size_t s1 = ((size_t)(b * CC + 1) * NSMALL + a1) * NSMALL + a2;
    float4 v = make_float4(fr[s0] * invp, fi[s0] * invp,
                           fr[s1] * invp, fi[s1] * invp);

    int j2v = (tid < 128) ? tid : tid + 256;        // nonzero staged col
    int j2z = (tid < 128) ? tid + 256 : tid;        // zero staged col
    s[nfft29781_brev9(j2v)] = v;
    s[nfft29781_brev9(j2z)] = make_float4(0.0f, 0.0f, 0.0f, 0.0f);
    __syncthreads();

    nfft29781_fft512_c2(s, tid);

    int q = a1 ^ 128;                               // compact row index
    uint2* Gr = Grows + ((size_t)b * NSMALL + q) * NGRID;
    float4 v0 = s[tid], v1 = s[tid + 256];
    uint2 pk0, pk1;
    pk0.x = nfft29781_bf16pack(v0.x, v0.y);  pk0.y = nfft29781_bf16pack(v0.z, v0.w);
    pk1.x = nfft29781_bf16pack(v1.x, v1.y);  pk1.y = nfft29781_bf16pack(v1.z, v1.w);
    Gr[tid]       = pk0;
    Gr[tid + 256] = pk1;
}

// ---------------------------------------------------------------------------
// Cols: one block per (b, 4-col group). Reads compact bf16 Grows (q=0..255
// maps to staged row r=(q<128)?q:q+256), injects zeros for middle rows,
// 4 concurrent fp32 FFTs, packs bf16x4 into Gcols[b][512][512].
// ---------------------------------------------------------------------------
__global__ __launch_bounds__(256) void nfft29781_cols3(const uint2* __restrict__ Grows,
                                                       uint2* __restrict__ Gcols) {
    __shared__ float4 s[4 * LPAD4];                 // 32.8 KB
    int tid  = threadIdx.x;
    int b    = blockIdx.x >> 7;
    int col0 = (blockIdx.x & 127) << 2;
    const uint2* Gr = Grows + (size_t)b * GROWS_B;

    #pragma unroll
    for (int it = 0; it < 4; ++it) {
        int e  = it * 256 + tid;                    // 0..1023
        int cp = e & 3;
        int q  = e >> 2;                            // 0..255 compact row
        int r  = (q < 128) ? q : q + 256;           // staged row
        s[cp * LPAD4 + nfft29781_brev9(r)] =
            nfft29781_unpk(Gr[(size_t)q * NGRID + col0 + cp]);
    }
    #pragma unroll
    for (int it = 0; it < 4; ++it) {                // zero the middle rows
        int e  = it * 256 + tid;
        int cp = e & 3;
        int q  = e >> 2;
        s[cp * LPAD4 + nfft29781_brev9(q + 128)] = make_float4(0.0f, 0.0f, 0.0f, 0.0f);
    }
    __syncthreads();

    int c = tid & 3;
    int w = tid >> 2;                               // 0..63
    float4* sc = s + c * LPAD4;
    for (int st = 0; st < 9; ++st) {
        int half = 1 << st;
        #pragma unroll
        for (int k = 0; k < 4; ++k) {
            int bf  = w + (k << 6);                 // 0..255
            int pos = bf & (half - 1);
            int i0  = ((bf >> st) << (st + 1)) + pos;
            int i1  = i0 + half;
            float ang = -(float)M_PI * (float)pos / (float)half;
            float sn, cs;
            __sincosf(ang, &sn, &cs);
            float4 a = sc[i0];
            float4 bb = sc[i1];
            float4 tw;
            tw.x = bb.x * cs - bb.y * sn;  tw.y = bb.x * sn + bb.y * cs;
            tw.z = bb.z * cs - bb.w * sn;  tw.w = bb.z * sn + bb.w * cs;
            sc[i0] = make_float4(a.x + tw.x, a.y + tw.y, a.z + tw.z, a.w + tw.w);
            sc[i1] = make_float4(a.x - tw.x, a.y - tw.y, a.z - tw.z, a.w - tw.w);
        }
        __syncthreads();
    }

    uint2* Gc = Gcols + (size_t)b * GCOLS_B;
    #pragma unroll
    for (int it = 0; it < 8; ++it) {
        int e  = it * 256 + tid;                    // 0..2047
        int cp = e & 3;
        int r  = e >> 2;                            // 0..511
        float4 v = s[cp * LPAD4 + r];
        uint2 pk;
        pk.x = nfft29781_bf16pack(v.x, v.y);        // ch0 re|im
        pk.y = nfft29781_bf16pack(v.z, v.w);        // ch1 re|im
        Gc[(size_t)r * NGRID + col0 + cp] = pk;
    }
}

// ---------------------------------------------------------------------------
// Gather: 8 lanes per point, TWO points per group (pp0=2k, pp1=2k+1) ->
// 16 tap-loads in flight per wave (2x MLP vs R10). Lane j owns column-tap j.
// Weights once per group per point; w0[i] broadcast via __shfl; 3-stage
// __shfl_xor butterfly; lane 0 writes planar out for both points.
// Weight sequence bit-matches reference ceil(x*n)-m.
// ---------------------------------------------------------------------------
__global__ __launch_bounds__(256) void nfft29781_gather_x2(const float* __restrict__ x,
                                                           const uint2* __restrict__ Gcols,
                                                           float* __restrict__ out,
                                                           int out_elems) {
    int t  = blockIdx.x * blockDim.x + threadIdx.x;
    int j  = t & 7;                  // my column tap
    int g2 = t >> 3;                 // group id
    int pp0 = g2 * 2;
    if (pp0 >= BB * MPTS) return;
    int pp1 = pp0 + 1;               // BB*MPTS even -> always valid

    const float bw = 1.5f * (float)M_PI;
    const float invpi = 1.0f / (float)M_PI;

    // ---- point 0 setup ----
    int b0  = (pp0 >= MPTS) ? 1 : 0;
    float u00 = x[(size_t)pp0 * 2 + 0] * (float)NGRID;
    float u01 = x[(size_t)pp0 * 2 + 1] * (float)NGRID;
    float c00 = ceilf(u00), c01 = ceilf(u01);
    int base00 = (int)c00 - MW, base01 = (int)c01 - MW;
    float d00 = c00 - u00, d01 = c01 - u01;
    float w0a, w1a;
    {
        float nk = (float)(MW - j) - d00;
        float tt = (float)(MW * MW) - nk * nk;
        w0a = 0.0f;
        if (tt > 0.0f) { float a = sqrtf(tt); float e = expf(bw * a);
                         w0a = (e - 1.0f / e) * 0.5f * invpi / a; }
        nk = (float)(MW - j) - d01;
        tt = (float)(MW * MW) - nk * nk;
        w1a = 0.0f;
        if (tt > 0.0f) { float a = sqrtf(tt); float e = expf(bw * a);
                         w1a = (e - 1.0f / e) * 0.5f * invpi / a; }
    }

    // ---- point 1 setup ----
    int b1  = (pp1 >= MPTS) ? 1 : 0;
    float u10 = x[(size_t)pp1 * 2 + 0] * (float)NGRID;
    float u11 = x[(size_t)pp1 * 2 + 1] * (float)NGRID;
    float c10 = ceilf(u10), c11 = ceilf(u11);
    int base10 = (int)c10 - MW, base11 = (int)c11 - MW;
    float d10 = c10 - u10, d11 = c11 - u11;
    float w0b, w1b;
    {
        float nk = (float)(MW - j) - d10;
        float tt = (float)(MW * MW) - nk * nk;
        w0b = 0.0f;
        if (tt > 0.0f) { float a = sqrtf(tt); float e = expf(bw * a);
                         w0b = (e - 1.0f / e) * 0.5f * invpi / a; }
        nk = (float)(MW - j) - d11;
        tt = (float)(MW * MW) - nk * nk;
        w1b = 0.0f;
        if (tt > 0.0f) { float a = sqrtf(tt); float e = expf(bw * a);
                         w1b = (e - 1.0f / e) * 0.5f * invpi / a; }
    }

    const uint2* Ga = Gcols + (size_t)b0 * GCOLS_B;
    const uint2* Gb = Gcols + (size_t)b1 * GCOLS_B;
    int cixa = (base01 + j) & (NGRID - 1);
    int cixb = (base11 + j) & (NGRID - 1);
    int lanebase = (threadIdx.x & 63) & ~7;

    float A0 = 0.0f, A1 = 0.0f, A2 = 0.0f, A3 = 0.0f;   // p0: ch0re,ch0im,ch1re,ch1im
    float B0 = 0.0f, B1 = 0.0f, B2 = 0.0f, B3 = 0.0f;   // p1
    #pragma unroll
    for (int i = 0; i < 8; ++i) {
        float wa = __shfl(w0a, lanebase + i, 64);
        float wb = __shfl(w0b, lanebase + i, 64);
        uint2 ga = Ga[(size_t)((((base00 + i) & (NGRID - 1)) << 9) + cixa)];
        uint2 gb = Gb[(size_t)((((base10 + i) & (NGRID - 1)) << 9) + cixb)];
        float4 ua = nfft29781_unpk(ga);
        float4 ub = nfft29781_unpk(gb);
        A0 += wa * ua.x;  A1 += wa * ua.y;  A2 += wa * ua.z;  A3 += wa * ua.w;
        B0 += wb * ub.x;  B1 += wb * ub.y;  B2 += wb * ub.z;  B3 += wb * ub.w;
    }
    A0 *= w1a;  A1 *= w1a;  A2 *= w1a;  A3 *= w1a;
    B0 *= w1b;  B1 *= w1b;  B2 *= w1b;  B3 *= w1b;

    #pragma unroll
    for (int msk = 1; msk < 8; msk <<= 1) {
        A0 += __shfl_xor(A0, msk, 64);  A1 += __shfl_xor(A1, msk, 64);
        A2 += __shfl_xor(A2, msk, 64);  A3 += __shfl_xor(A3, msk, 64);
        B0 += __shfl_xor(B0, msk, 64);  B1 += __shfl_xor(B1, msk, 64);
        B2 += __shfl_xor(B2, msk, 64);  B3 += __shfl_xor(B3, msk, 64);
    }

    if (j == 0) {
        int pt0 = pp0 - b0 * MPTS;
        int pt1 = pp1 - b1 * MPTS;
        size_t o00 = (size_t)(b0 * CC) * MPTS + pt0;     // p0 ch0
        size_t o01 = o00 + MPTS;                          // p0 ch1
        size_t o10 = (size_t)(b1 * CC) * MPTS + pt1;     // p1 ch0
        size_t o11 = o10 + MPTS;                          // p1 ch1
        if (o00 < (size_t)out_elems)         out[o00]         = A0;
        if (PLANE + o00 < (size_t)out_elems) out[PLANE + o00] = A1;
        if (o01 < (size_t)out_elems)         out[o01]         = A2;
        if (PLANE + o01 < (size_t)out_elems) out[PLANE + o01] = A3;
        if (o10 < (size_t)out_elems)         out[o10]         = B0;
        if (PLANE + o10 < (size_t)out_elems) out[PLANE + o10] = B1;
        if (o11 < (size_t)out_elems)         out[o11]         = B2;
        if (PLANE + o11 < (size_t)out_elems) out[PLANE + o11] = B3;
    }
}

extern "C" void kernel_launch(void* const* d_in, const int* in_sizes, int n_in,
                              void* d_out, int out_size, void* d_ws, size_t ws_size,
                              hipStream_t stream) {
    (void)in_sizes; (void)n_in;
    const float* x  = (const float*)d_in[0];
    const float* fr = (const float*)d_in[1];
    const float* fi = (const float*)d_in[2];
    float* out  = (float*)d_out;
    uint2* Grows = (uint2*)d_ws;                 // 2 MB
    uint2* Gcols = (uint2*)d_ws + GCOLS_OFF;     // 4 MB @ +2 MB

    if (ws_size < (size_t)8 * 1024 * 1024) return;   // diagnostic no-op

    nfft29781_rows3<<<BB * NSMALL, 256, 0, stream>>>(fr, fi, Grows);
    nfft29781_cols3<<<BB * (NGRID / 4), 256, 0, stream>>>(Grows, Gcols);
    int gthreads = (BB * MPTS / 2) * 8;          // 8 lanes per 2-point group
    nfft29781_gather_x2<<<(gthreads + 255) / 256, 256, 0, stream>>>(
        x, Gcols, out, out_size);
}